// Round 1
// baseline (62.429 us; speedup 1.0000x reference)
//
#include <hip/hip_runtime.h>

#define NB    32
#define NKEYS 2048
#define DKH   512    // DK == DQ == DV == H == 512
#define NCHUNK 32    // n-dim split for the V contraction
#define ROWS_PER_CHUNK (NKEYS / NCHUNK)   // 64

__device__ __forceinline__ float wave_sum(float v) {
    #pragma unroll
    for (int o = 32; o > 0; o >>= 1) v += __shfl_xor(v, o);
    return v;
}
__device__ __forceinline__ float wave_max(float v) {
    #pragma unroll
    for (int o = 32; o > 0; o >>= 1) v = fmaxf(v, __shfl_xor(v, o));
    return v;
}

// wkh[dk] = sum_h Wk[dk,h]*Wh[h];  wqh[dk] = sum_h Wq[dk,h]*Wh[h]
// grid: 512 blocks x 64 threads (1 wave)
__global__ void prep_w_kernel(const float* __restrict__ Wk, const float* __restrict__ Wq,
                              const float* __restrict__ Wh,
                              float* __restrict__ wkh, float* __restrict__ wqh) {
    int dk = blockIdx.x;
    int lane = threadIdx.x;
    float sk = 0.f, sq = 0.f;
    #pragma unroll
    for (int h = lane; h < DKH; h += 64) {
        float wh = Wh[h];
        sk = fmaf(Wk[dk * DKH + h], wh, sk);
        sq = fmaf(Wq[dk * DKH + h], wh, sq);
    }
    sk = wave_sum(sk);
    sq = wave_sum(sq);
    if (lane == 0) { wkh[dk] = sk; wqh[dk] = sq; }
}

// qdot[b] = Q[b,:]·wqh + (bk+bq)·Wh + bh
// grid: 32 blocks x 64 threads
__global__ void prep_q_kernel(const float* __restrict__ Q, const float* __restrict__ bk,
                              const float* __restrict__ bq, const float* __restrict__ bh,
                              const float* __restrict__ Wh, const float* __restrict__ wqh,
                              float* __restrict__ qdot) {
    int b = blockIdx.x;
    int lane = threadIdx.x;
    float s = 0.f;
    #pragma unroll
    for (int h = lane; h < DKH; h += 64) s = fmaf(bk[h] + bq[h], Wh[h], s);
    #pragma unroll
    for (int d = lane; d < DKH; d += 64) s = fmaf(Q[b * DKH + d], wqh[d], s);
    s = wave_sum(s);
    if (lane == 0) qdot[b] = s + bh[0];
}

// e[b,n] = relu( K[b,n,:]·wkh + qdot[b] )   — one wave per row, 4 rows/block
// grid: (NB*NKEYS)/4 = 16384 blocks x 256 threads
__global__ __launch_bounds__(256) void energy_kernel(const float* __restrict__ K,
        const float* __restrict__ wkh, const float* __restrict__ qdot,
        float* __restrict__ e) {
    int tid  = threadIdx.x;
    int lane = tid & 63, wv = tid >> 6;
    long row = (long)blockIdx.x * 4 + wv;          // 0 .. 65535
    int b = (int)(row >> 11);
    const float4* kr = (const float4*)(K + row * DKH);
    const float4* wr = (const float4*)wkh;
    float4 k0 = kr[lane],      w0 = wr[lane];
    float4 k1 = kr[lane + 64], w1 = wr[lane + 64];
    float s = k0.x * w0.x + k0.y * w0.y + k0.z * w0.z + k0.w * w0.w;
    s += k1.x * w1.x + k1.y * w1.y + k1.z * w1.z + k1.w * w1.w;
    s = wave_sum(s);
    if (lane == 0) e[row] = fmaxf(s + qdot[b], 0.f);
}

// weights[b,:] = softmax(e[b,:])  — one block per batch
// grid: 32 blocks x 256 threads
__global__ __launch_bounds__(256) void softmax_kernel(const float* __restrict__ e,
        float* __restrict__ wout) {
    int b = blockIdx.x, tid = threadIdx.x;
    int lane = tid & 63, wv = tid >> 6;
    const float4* er = (const float4*)(e + b * NKEYS);
    float4 v0 = er[tid], v1 = er[tid + 256];

    __shared__ float sred[4];
    float m = fmaxf(fmaxf(fmaxf(v0.x, v0.y), fmaxf(v0.z, v0.w)),
                    fmaxf(fmaxf(v1.x, v1.y), fmaxf(v1.z, v1.w)));
    m = wave_max(m);
    if (lane == 0) sred[wv] = m;
    __syncthreads();
    m = fmaxf(fmaxf(sred[0], sred[1]), fmaxf(sred[2], sred[3]));
    __syncthreads();

    float4 p0, p1;
    p0.x = expf(v0.x - m); p0.y = expf(v0.y - m);
    p0.z = expf(v0.z - m); p0.w = expf(v0.w - m);
    p1.x = expf(v1.x - m); p1.y = expf(v1.y - m);
    p1.z = expf(v1.z - m); p1.w = expf(v1.w - m);
    float s = p0.x + p0.y + p0.z + p0.w + p1.x + p1.y + p1.z + p1.w;
    s = wave_sum(s);
    if (lane == 0) sred[wv] = s;
    __syncthreads();
    s = sred[0] + sred[1] + sred[2] + sred[3];
    float inv = 1.f / s;

    float4* wo = (float4*)(wout + b * NKEYS);
    p0.x *= inv; p0.y *= inv; p0.z *= inv; p0.w *= inv;
    p1.x *= inv; p1.y *= inv; p1.z *= inv; p1.w *= inv;
    wo[tid] = p0;
    wo[tid + 256] = p1;
}

// partial[b,chunk,v] = sum_{n in chunk} w[b,n] * V[b,n,v]
// grid: NB*NCHUNK = 1024 blocks x 256 threads; thread t owns v = 2t, 2t+1
__global__ __launch_bounds__(256) void weightedv_kernel(const float* __restrict__ V,
        const float* __restrict__ w, float* __restrict__ partial) {
    int chunk = blockIdx.x & (NCHUNK - 1);
    int b     = blockIdx.x >> 5;
    int tid   = threadIdx.x;
    int n0    = chunk * ROWS_PER_CHUNK;
    const float2* vb = (const float2*)(V + ((long)b * NKEYS + n0) * DKH);
    const float*  wb = w + b * NKEYS + n0;
    float2 acc = {0.f, 0.f};
    #pragma unroll 4
    for (int r = 0; r < ROWS_PER_CHUNK; ++r) {
        float wt = wb[r];
        float2 vv = vb[r * (DKH / 2) + tid];
        acc.x = fmaf(wt, vv.x, acc.x);
        acc.y = fmaf(wt, vv.y, acc.y);
    }
    ((float2*)(partial + ((long)(b * NCHUNK + chunk)) * DKH))[tid] = acc;
}

// out[b,v] = sum_c partial[b,c,v]
// grid: (NB*DKH)/256 = 64 blocks x 256 threads
__global__ void reduce_kernel(const float* __restrict__ partial, float* __restrict__ out) {
    int i = blockIdx.x * 256 + threadIdx.x;   // 0 .. 16383
    int b = i >> 9;
    int v = i & 511;
    float s = 0.f;
    #pragma unroll
    for (int c = 0; c < NCHUNK; ++c) s += partial[(long)((b * NCHUNK + c) << 9) + v];
    out[i] = s;
}

extern "C" void kernel_launch(void* const* d_in, const int* in_sizes, int n_in,
                              void* d_out, int out_size, void* d_ws, size_t ws_size,
                              hipStream_t stream) {
    const float* Q  = (const float*)d_in[0];
    const float* K  = (const float*)d_in[1];
    const float* V  = (const float*)d_in[2];
    const float* Wk = (const float*)d_in[3];
    const float* bk = (const float*)d_in[4];
    const float* Wq = (const float*)d_in[5];
    const float* bq = (const float*)d_in[6];
    const float* Wh = (const float*)d_in[7];
    const float* bh = (const float*)d_in[8];

    float* out  = (float*)d_out;              // [32, 512]  (output first)
    float* wout = out + NB * DKH;             // [32, 2048] (weights second)

    float* ws      = (float*)d_ws;
    float* wkh     = ws;                      // 512
    float* wqh     = ws + 512;                // 512
    float* qdot    = ws + 1024;               // 32
    float* e       = ws + 2048;               // 65536
    float* partial = ws + 2048 + NB * NKEYS;  // 32*32*512 = 524288

    prep_w_kernel<<<DKH, 64, 0, stream>>>(Wk, Wq, Wh, wkh, wqh);
    prep_q_kernel<<<NB, 64, 0, stream>>>(Q, bk, bq, bh, Wh, wqh, qdot);
    energy_kernel<<<(NB * NKEYS) / 4, 256, 0, stream>>>(K, wkh, qdot, e);
    softmax_kernel<<<NB, 256, 0, stream>>>(e, wout);
    weightedv_kernel<<<NB * NCHUNK, 256, 0, stream>>>(V, wout, partial);
    reduce_kernel<<<(NB * DKH) / 256, 256, 0, stream>>>(partial, out);
}